// Round 2
// baseline (1320.904 us; speedup 1.0000x reference)
//
#include <hip/hip_runtime.h>
#include <math.h>

// Problem constants (fixed by the reference)
#define M_TOT  32400
#define CKDIM  64
#define QTOT   1620
#define OCDIM  1536      // O*CV = 3*512
#define TOPK   20
#define NSPLIT 36
#define NS     (NSPLIT*TOPK)   // 720 partial candidates per query
#define MHALF  16200

__device__ __forceinline__ float bf2f(unsigned short u) {
    union { unsigned int i; float f; } v;
    v.i = ((unsigned int)u) << 16;
    return v.f;
}

__device__ __forceinline__ unsigned short f2bf(float f) {
    union { float f; unsigned int i; } u;
    u.f = f;
    unsigned int r = u.i + 0x7FFF + ((u.i >> 16) & 1);  // RTNE
    return (unsigned short)(r >> 16);
}

__device__ __forceinline__ float ldval(const float* p, int i)          { return p[i]; }
__device__ __forceinline__ float ldval(const unsigned short* p, int i) { return bf2f(p[i]); }

// ---------------------------------------------------------------------------
// K_flag: detect whether inputs are fp32 (flag=1) or bf16 (flag=0).
// Reading fp32 data as bf16 yields uniform-random 16-bit words in even slots:
// P(all 64 stay finite and |v|<=64) ~ 6e-19.
// ---------------------------------------------------------------------------
__global__ void k_flag(const unsigned short* __restrict__ qk_u, int* __restrict__ flag) {
    if (threadIdx.x == 0) {
        int f = 0;
        for (int i = 0; i < 128; ++i) {
            float v = bf2f(qk_u[i]);
            if (!(fabsf(v) <= 64.f)) f = 1;   // catches NaN/Inf too
        }
        flag[0] = f;
    }
}

// ---------------------------------------------------------------------------
// K0: a_sq[m] = sum_c mk[c][m]^2
// ---------------------------------------------------------------------------
__global__ __launch_bounds__(256) void k_asq(const void* __restrict__ mk_,
                                             const int* __restrict__ flag,
                                             float* __restrict__ asq) {
    int m = blockIdx.x * 256 + threadIdx.x;
    if (m >= M_TOT) return;
    float s = 0.f;
    if (flag[0]) {
        const float* mk = (const float*)mk_;
        for (int c = 0; c < CKDIM; ++c) { float v = mk[c * M_TOT + m]; s += v * v; }
    } else {
        const unsigned short* mk = (const unsigned short*)mk_;
        for (int c = 0; c < CKDIM; ++c) { float v = bf2f(mk[c * M_TOT + m]); s += v * v; }
    }
    asq[m] = s;
}

// Branchless insert of (cv, ci) into descending-sorted top-20 in registers.
__device__ __forceinline__ void insert20(float (&tv)[TOPK], int (&ti)[TOPK],
                                         float cv, int ci) {
    if (cv <= tv[TOPK - 1]) return;
    #pragma unroll
    for (int j = TOPK - 1; j >= 1; --j) {
        bool sj = tv[j] >= cv;
        bool sp = tv[j - 1] >= cv;
        float nv = sj ? tv[j] : (sp ? cv : tv[j - 1]);
        int   ni = sj ? ti[j] : (sp ? ci : ti[j - 1]);
        tv[j] = nv; ti[j] = ni;
    }
    bool s0 = tv[0] >= cv;
    float nv0 = s0 ? tv[0] : cv;
    int   ni0 = s0 ? ti[0] : ci;
    tv[0] = nv0; ti[0] = ni0;
}

template <typename T>
__device__ __forceinline__ void scan_split(const T* __restrict__ mk,
                                           const float* __restrict__ asq,
                                           const float* __restrict__ qs, int tid,
                                           int m_lo, int m_hi,
                                           float (&tv)[TOPK], int (&ti)[TOPK]) {
    int m = m_lo;
    for (; m + 16 <= m_hi; m += 16) {
        float acc[16];
        #pragma unroll
        for (int t = 0; t < 16; ++t) acc[t] = -0.5f * asq[m + t];
        for (int c = 0; c < CKDIM; ++c) {
            float qc = qs[c * 256 + tid];
            const T* row = mk + (size_t)c * M_TOT + m;
            #pragma unroll
            for (int t = 0; t < 16; ++t) acc[t] += ldval(row, t) * qc;
        }
        #pragma unroll
        for (int t = 0; t < 16; ++t)
            insert20(tv, ti, acc[t] * 0.25f, m + t);   // (2*ab - asq)/8
    }
    for (; m < m_hi; ++m) {
        float a0 = -0.5f * asq[m];
        for (int c = 0; c < CKDIM; ++c)
            a0 += ldval(mk, (size_t)c * M_TOT + m) * qs[c * 256 + tid];
        insert20(tv, ti, a0 * 0.25f, m);
    }
}

// ---------------------------------------------------------------------------
// K1: per (query, m-split) partial top-20 of affinity.
// grid = (7 q-blocks, 36 splits); block = 256 threads; thread <-> query.
// mk addresses are wave-uniform -> scalar/broadcast loads.
// ---------------------------------------------------------------------------
__global__ __launch_bounds__(256) void k_topk(const void* __restrict__ mk_,
                                              const void* __restrict__ qk_,
                                              const int* __restrict__ flag,
                                              const float* __restrict__ asq,
                                              float* __restrict__ pval,
                                              unsigned short* __restrict__ pidx) {
    __shared__ float qs[CKDIM * 256];   // 65536 B: qs[c][tid] = qk[c][q0+tid] as fp32
    const int tid = threadIdx.x;
    const int q0  = blockIdx.x * 256;
    const int sp  = blockIdx.y;
    const bool isf = flag[0] != 0;
    const int q = q0 + tid;

    if (isf) {
        const float* qk = (const float*)qk_;
        for (int c = 0; c < CKDIM; ++c)
            qs[c * 256 + tid] = (q < QTOT) ? qk[c * QTOT + q] : 0.f;
    } else {
        const unsigned short* qk = (const unsigned short*)qk_;
        for (int c = 0; c < CKDIM; ++c)
            qs[c * 256 + tid] = (q < QTOT) ? bf2f(qk[c * QTOT + q]) : 0.f;
    }
    __syncthreads();
    if (q >= QTOT) return;

    const int m_lo = sp * (M_TOT / NSPLIT);        // 32400/36 = 900 exactly
    const int m_hi = m_lo + (M_TOT / NSPLIT);

    float tv[TOPK];
    int   ti[TOPK];
    #pragma unroll
    for (int j = 0; j < TOPK; ++j) { tv[j] = -INFINITY; ti[j] = 0; }

    if (isf) scan_split((const float*)mk_,          asq, qs, tid, m_lo, m_hi, tv, ti);
    else     scan_split((const unsigned short*)mk_, asq, qs, tid, m_lo, m_hi, tv, ti);

    float*          pv = pval + (size_t)q * NS + sp * TOPK;
    unsigned short* pi = pidx + (size_t)q * NS + sp * TOPK;
    #pragma unroll
    for (int j = 0; j < TOPK; ++j) { pv[j] = tv[j]; pi[j] = (unsigned short)ti[j]; }
}

// ---------------------------------------------------------------------------
// K2: merge 36 partial top-20 lists -> global top-20 + softmax.
// One 64-lane wave per query. Weights stored k-major: wq[k][q], iq[k][q].
// ---------------------------------------------------------------------------
__global__ __launch_bounds__(64) void k_merge(const float* __restrict__ pval,
                                              const unsigned short* __restrict__ pidx,
                                              float* __restrict__ wq,
                                              int* __restrict__ iq) {
    const int q    = blockIdx.x;
    const int lane = threadIdx.x;
    __shared__ float sv[NS];
    __shared__ int   si[NS];

    for (int s = lane; s < NS; s += 64) {
        sv[s] = pval[(size_t)q * NS + s];
        si[s] = (int)pidx[(size_t)q * NS + s];
    }
    __syncthreads();

    float keep_v = -INFINITY;
    int   keep_i = 0;
    float maxv   = 0.f;

    for (int r = 0; r < TOPK; ++r) {
        float bv = -INFINITY;
        int   bs = NS;
        #pragma unroll
        for (int it = 0; it < (NS + 63) / 64; ++it) {
            int s = lane + it * 64;
            if (s < NS) {
                float v = sv[s];
                if (v > bv) { bv = v; bs = s; }
            }
        }
        #pragma unroll
        for (int off = 32; off; off >>= 1) {
            float ov = __shfl_xor(bv, off);
            int   os = __shfl_xor(bs, off);
            if (ov > bv || (ov == bv && os < bs)) { bv = ov; bs = os; }
        }
        if (r == 0) maxv = bv;
        if (lane == r) { keep_v = bv; keep_i = si[bs]; }
        if (lane == 0) sv[bs] = -INFINITY;
        __syncthreads();
    }

    float e = (lane < TOPK) ? __expf(keep_v - maxv) : 0.f;
    float sum = e;
    #pragma unroll
    for (int off = 32; off; off >>= 1) sum += __shfl_xor(sum, off);

    if (lane < TOPK) {
        wq[(size_t)lane * QTOT + q] = e / sum;
        iq[(size_t)lane * QTOT + q] = keep_i;
    }
}

// ---------------------------------------------------------------------------
// K3: readout. Block per oc row; V row staged in LDS in two half-passes so the
// fp32 row (129.6 KB) fits the 64 KB block LDS limit. Lanes over q ->
// coalesced weight reads and out writes.
// ---------------------------------------------------------------------------
__global__ __launch_bounds__(256) void k_readout(const void* __restrict__ mv_,
                                                 const int* __restrict__ flag,
                                                 const float* __restrict__ wq,
                                                 const int* __restrict__ iq,
                                                 void* __restrict__ out_) {
    __shared__ float rowbuf[MHALF];   // 64800 B
    const int oc  = blockIdx.x;
    const int tid = threadIdx.x;
    const bool isf = flag[0] != 0;

    float acc[7];
    #pragma unroll
    for (int j = 0; j < 7; ++j) acc[j] = 0.f;

    for (int pass = 0; pass < 2; ++pass) {
        const int base = pass * MHALF;
        __syncthreads();   // protect previous pass's reads before restaging
        if (isf) {
            const uint4* s4 = (const uint4*)((const float*)mv_ + (size_t)oc * M_TOT + base);
            uint4* d4 = (uint4*)rowbuf;
            for (int i = tid; i < MHALF / 4; i += 256) d4[i] = s4[i];   // 4050 x 16B
        } else {
            const uint4* s4 = (const uint4*)((const unsigned short*)mv_ + (size_t)oc * M_TOT + base);
            uint4* d4 = (uint4*)rowbuf;
            for (int i = tid; i < MHALF / 8; i += 256) d4[i] = s4[i];   // 2025 x 16B
        }
        __syncthreads();
        const unsigned short* rowu = (const unsigned short*)rowbuf;

        for (int j = 0; j < 7; ++j) {
            int q = tid + j * 256;
            if (q >= QTOT) break;
            float a = 0.f;
            #pragma unroll
            for (int k = 0; k < TOPK; ++k) {
                int idx = iq[(size_t)k * QTOT + q];
                if (idx >= base && idx < base + MHALF) {
                    float w = wq[(size_t)k * QTOT + q];
                    float v = isf ? rowbuf[idx - base] : bf2f(rowu[idx - base]);
                    a += w * v;
                }
            }
            acc[j] += a;
        }
    }

    for (int j = 0; j < 7; ++j) {
        int q = tid + j * 256;
        if (q >= QTOT) break;
        if (isf) ((float*)out_)[(size_t)oc * QTOT + q] = acc[j];
        else     ((unsigned short*)out_)[(size_t)oc * QTOT + q] = f2bf(acc[j]);
    }
}

// ---------------------------------------------------------------------------
extern "C" void kernel_launch(void* const* d_in, const int* in_sizes, int n_in,
                              void* d_out, int out_size, void* d_ws, size_t ws_size,
                              hipStream_t stream) {
    const void* qk = d_in[0];   // [64][1620]
    const void* mk = d_in[1];   // [64][32400]
    const void* mv = d_in[2];   // [1536][32400]

    char* ws = (char*)d_ws;
    int*            flag = (int*)ws;                                  // 256 B
    float*          asq  = (float*)(ws + 256);                        // 129,600 B
    float*          pval = (float*)(ws + 131072);                     // 1620*720*4 = 4,665,600 B
    unsigned short* pidx = (unsigned short*)(ws + 131072 + 4665600);  // 1620*720*2 = 2,332,800 B
    float*          wq   = (float*)(ws + 131072 + 4665600 + 2332800);          // 129,600 B
    int*            iq   = (int*)(ws + 131072 + 4665600 + 2332800 + 131072);   // 129,600 B
    // total ~= 7.4 MB

    k_flag   <<<dim3(1),                    dim3(64),  0, stream>>>((const unsigned short*)qk, flag);
    k_asq    <<<dim3((M_TOT + 255) / 256),  dim3(256), 0, stream>>>(mk, flag, asq);
    k_topk   <<<dim3(7, NSPLIT),            dim3(256), 0, stream>>>(mk, qk, flag, asq, pval, pidx);
    k_merge  <<<dim3(QTOT),                 dim3(64),  0, stream>>>(pval, pidx, wq, iq);
    k_readout<<<dim3(OCDIM),                dim3(256), 0, stream>>>(mv, flag, wq, iq, d_out);
}

// Round 3
// 981.545 us; speedup vs baseline: 1.3457x; 1.3457x over previous
//
#include <hip/hip_runtime.h>
#include <math.h>

// Problem constants (fixed by the reference; inputs confirmed fp32 in round 2)
#define M_TOT   32400
#define CKDIM   64
#define QTOT    1620
#define QPAD    1792      // 7 q-blocks x 256
#define OCDIM   1536      // O*CV = 3*512
#define TOPK    20
#define NSPLIT  75        // 32400/75 = 432 m per split
#define MSPLIT  432
#define MCHUNK  48        // 3 MFMA m-tiles; 432/48 = 9 chunks
#define KSPLIT  10        // approx top-K kept per (query, split)
#define NS      (NSPLIT*KSPLIT)   // 750 candidates per query
#define POOL    40        // approx-global pool rescored exactly
#define LDSTR   49        // aff row stride (floats): 2-way bank aliasing = free
#define MHALF   16200

typedef __attribute__((ext_vector_type(8))) short bf16x8;  // 8 bf16 (4 VGPRs)
typedef __attribute__((ext_vector_type(4))) float f32x4;

__device__ __forceinline__ unsigned short f2bf(float f) {
    union { float f; unsigned int i; } u;
    u.f = f;
    unsigned int r = u.i + 0x7FFF + ((u.i >> 16) & 1);  // RTNE
    return (unsigned short)(r >> 16);
}

// ---------------------------------------------------------------------------
// K_cast: build bf16 transposed copies.
//   mkT[m][c] = bf16(mk[c][m])   (32400 x 64)
//   qkT[q][c] = bf16(qk[c][q])   (1792 x 64, rows >= 1620 zeroed)
// ---------------------------------------------------------------------------
__global__ __launch_bounds__(256) void k_cast(const float* __restrict__ mk,
                                              const float* __restrict__ qk,
                                              unsigned short* __restrict__ mkT,
                                              unsigned short* __restrict__ qkT) {
    int idx = blockIdx.x * 256 + threadIdx.x;
    if (idx < M_TOT) {
        int m = idx;
        unsigned short tmp[CKDIM];
        #pragma unroll
        for (int c = 0; c < CKDIM; ++c) tmp[c] = f2bf(mk[c * M_TOT + m]);
        uint4* dst = (uint4*)(mkT + (size_t)m * CKDIM);
        #pragma unroll
        for (int i = 0; i < CKDIM / 8; ++i) dst[i] = ((const uint4*)tmp)[i];
    } else if (idx < M_TOT + QPAD) {
        int q = idx - M_TOT;
        unsigned short tmp[CKDIM];
        #pragma unroll
        for (int c = 0; c < CKDIM; ++c)
            tmp[c] = (q < QTOT) ? f2bf(qk[c * QTOT + q]) : (unsigned short)0;
        uint4* dst = (uint4*)(qkT + (size_t)q * CKDIM);
        #pragma unroll
        for (int i = 0; i < CKDIM / 8; ++i) dst[i] = ((const uint4*)tmp)[i];
    }
}

// ---------------------------------------------------------------------------
// K0: a_sq[m] = sum_c mk[c][m]^2  (fp32 exact)
// ---------------------------------------------------------------------------
__global__ __launch_bounds__(256) void k_asq(const float* __restrict__ mk,
                                             float* __restrict__ asq) {
    int m = blockIdx.x * 256 + threadIdx.x;
    if (m >= M_TOT) return;
    float s = 0.f;
    #pragma unroll
    for (int c = 0; c < CKDIM; ++c) { float v = mk[c * M_TOT + m]; s += v * v; }
    asq[m] = s;
}

// Branchless insert into descending-sorted top-10 (caller guards cv > tv[9]).
__device__ __forceinline__ void insert10(float (&tv)[KSPLIT], int (&ti)[KSPLIT],
                                         float cv, int ci) {
    #pragma unroll
    for (int j = KSPLIT - 1; j >= 1; --j) {
        bool sj = tv[j] >= cv;
        bool sp = tv[j - 1] >= cv;
        float nv = sj ? tv[j] : (sp ? cv : tv[j - 1]);
        int   ni = sj ? ti[j] : (sp ? ci : ti[j - 1]);
        tv[j] = nv; ti[j] = ni;
    }
    bool s0 = tv[0] >= cv;
    float nv0 = s0 ? tv[0] : cv;
    int   ni0 = s0 ? ti[0] : ci;
    tv[0] = nv0; ti[0] = ni0;
}

// ---------------------------------------------------------------------------
// K1: MFMA approx affinity + per-(query,split) top-10.
// grid = (7, 75); block = 256 = 4 fully independent waves (no barriers).
// Score = dot(mk_m, qk_q) - 0.5*asq[m]  (monotone transform of affinity).
// A-operand = mkT rows (D rows = m), B-operand = qkT rows (D cols = q).
// C/D layout: col=lane&15 (q), row=quad*4+reg (m) [m89].
// ---------------------------------------------------------------------------
__global__ __launch_bounds__(256) void k_topk_mfma(const unsigned short* __restrict__ mkT,
                                                   const unsigned short* __restrict__ qkT,
                                                   const float* __restrict__ asq,
                                                   _Float16* __restrict__ pvalh,
                                                   unsigned short* __restrict__ pidx) {
    __shared__ float aff[256 * LDSTR];   // 50,176 B
    const int tid  = threadIdx.x;
    const int lane = tid & 63;
    const int w    = tid >> 6;
    const int l15  = lane & 15;
    const int quad = lane >> 4;
    const int q0   = blockIdx.x * 256;
    const int sp   = blockIdx.y;
    const int m_base = sp * MSPLIT;

    // B-frags (qk side) — loop-invariant, kept in registers.
    bf16x8 bF[4][2];
    #pragma unroll
    for (int qt = 0; qt < 4; ++qt) {
        const unsigned short* p = qkT + (size_t)(q0 + w * 64 + qt * 16 + l15) * CKDIM + quad * 8;
        bF[qt][0] = *(const bf16x8*)(p);
        bF[qt][1] = *(const bf16x8*)(p + 32);
    }

    float tv[KSPLIT];
    int   ti[KSPLIT];
    #pragma unroll
    for (int j = 0; j < KSPLIT; ++j) { tv[j] = -INFINITY; ti[j] = 0; }

    for (int ch = 0; ch < MSPLIT / MCHUNK; ++ch) {
        const int m0 = m_base + ch * MCHUNK;
        #pragma unroll
        for (int mt = 0; mt < 3; ++mt) {
            const int mrow = m0 + mt * 16;
            f32x4 aq = *(const f32x4*)(asq + mrow + quad * 4);
            f32x4 cinit = -0.5f * aq;
            const unsigned short* pa = mkT + (size_t)(mrow + l15) * CKDIM + quad * 8;
            bf16x8 aF0 = *(const bf16x8*)(pa);
            bf16x8 aF1 = *(const bf16x8*)(pa + 32);
            #pragma unroll
            for (int qt = 0; qt < 4; ++qt) {
                f32x4 c = cinit;
                c = __builtin_amdgcn_mfma_f32_16x16x32_bf16(aF0, bF[qt][0], c, 0, 0, 0);
                c = __builtin_amdgcn_mfma_f32_16x16x32_bf16(aF1, bF[qt][1], c, 0, 0, 0);
                // rows m = mt*16 + quad*4 + r; col q_local = w*64 + qt*16 + l15
                float* dst = &aff[(w * 64 + qt * 16 + l15) * LDSTR + mt * 16 + quad * 4];
                dst[0] = c[0]; dst[1] = c[1]; dst[2] = c[2]; dst[3] = c[3];
            }
        }
        // Scan own row (written by this wave only — wave-internal ordering).
        const float* row = &aff[tid * LDSTR];
        #pragma unroll 8
        for (int m = 0; m < MCHUNK; ++m) {
            float v = row[m];
            if (v > tv[KSPLIT - 1]) insert10(tv, ti, v, m0 + m);
        }
    }

    _Float16*       pv = pvalh + (size_t)(q0 + tid) * NS + sp * KSPLIT;
    unsigned short* pi = pidx  + (size_t)(q0 + tid) * NS + sp * KSPLIT;
    #pragma unroll
    for (int j = 0; j < KSPLIT; ++j) {
        pv[j] = (_Float16)tv[j];
        pi[j] = (unsigned short)ti[j];
    }
}

// ---------------------------------------------------------------------------
// K2: per query, approx-global top-40 candidate pool (indices only).
// One 64-lane wave per query.
// ---------------------------------------------------------------------------
__global__ __launch_bounds__(64) void k_merge(const _Float16* __restrict__ pvalh,
                                              const unsigned short* __restrict__ pidx,
                                              int* __restrict__ cidx) {
    const int q    = blockIdx.x;
    const int lane = threadIdx.x;
    __shared__ float sv[NS];
    __shared__ int   si[NS];

    for (int s = lane; s < NS; s += 64) {
        sv[s] = (float)pvalh[(size_t)q * NS + s];
        si[s] = (int)pidx[(size_t)q * NS + s];
    }
    __syncthreads();

    for (int r = 0; r < POOL; ++r) {
        float bv = -INFINITY;
        int   bs = NS;
        #pragma unroll
        for (int it = 0; it < (NS + 63) / 64; ++it) {
            int s = lane + it * 64;
            if (s < NS) {
                float v = sv[s];
                if (v > bv) { bv = v; bs = s; }
            }
        }
        #pragma unroll
        for (int off = 32; off; off >>= 1) {
            float ov = __shfl_xor(bv, off);
            int   os = __shfl_xor(bs, off);
            if (ov > bv || (ov == bv && os < bs)) { bv = ov; bs = os; }
        }
        if (lane == 0) {
            cidx[(size_t)q * POOL + r] = si[bs];
            sv[bs] = -INFINITY;
        }
        __syncthreads();
    }
}

// ---------------------------------------------------------------------------
// K3: exact fp32 rescore of the 40-candidate pool; exact top-20 + softmax.
// One 64-lane wave per query; lane <-> candidate. All data L2-hot.
// ---------------------------------------------------------------------------
__global__ __launch_bounds__(64) void k_rescore(const float* __restrict__ mk,
                                                const float* __restrict__ qk,
                                                const float* __restrict__ asq,
                                                const int* __restrict__ cidx,
                                                float* __restrict__ wq,
                                                int* __restrict__ iq) {
    const int q    = blockIdx.x;
    const int lane = threadIdx.x;
    const int m_l  = (lane < POOL) ? cidx[(size_t)q * POOL + lane] : 0;

    float dot = 0.f;
    #pragma unroll
    for (int c = 0; c < CKDIM; ++c)
        dot += mk[(size_t)c * M_TOT + m_l] * qk[c * QTOT + q];
    float aff = (lane < POOL) ? (2.f * dot - asq[m_l]) * 0.125f : -INFINITY;

    __shared__ float kv[TOPK];
    __shared__ int   ki[TOPK];

    for (int r = 0; r < TOPK; ++r) {
        float bv = aff;
        int   bm = m_l;
        #pragma unroll
        for (int off = 32; off; off >>= 1) {
            float ov = __shfl_xor(bv, off);
            int   om = __shfl_xor(bm, off);
            if (ov > bv || (ov == bv && om < bm)) { bv = ov; bm = om; }
        }
        if (aff == bv && m_l == bm) aff = -INFINITY;   // deactivate winner (m unique)
        if (lane == 0) { kv[r] = bv; ki[r] = bm; }
    }
    __syncthreads();

    float e = (lane < TOPK) ? __expf(kv[lane] - kv[0]) : 0.f;
    float sum = e;
    #pragma unroll
    for (int off = 32; off; off >>= 1) sum += __shfl_xor(sum, off);

    if (lane < TOPK) {
        wq[(size_t)lane * QTOT + q] = e / sum;
        iq[(size_t)lane * QTOT + q] = ki[lane];
    }
}

// ---------------------------------------------------------------------------
// K4: readout. Block per oc row; V row staged in LDS in two half-passes.
// ---------------------------------------------------------------------------
__global__ __launch_bounds__(256) void k_readout(const float* __restrict__ mv,
                                                 const float* __restrict__ wq,
                                                 const int* __restrict__ iq,
                                                 float* __restrict__ out) {
    __shared__ float rowbuf[MHALF];   // 64,800 B
    const int oc  = blockIdx.x;
    const int tid = threadIdx.x;

    float acc[7];
    #pragma unroll
    for (int j = 0; j < 7; ++j) acc[j] = 0.f;

    for (int pass = 0; pass < 2; ++pass) {
        const int base = pass * MHALF;
        __syncthreads();
        const uint4* s4 = (const uint4*)(mv + (size_t)oc * M_TOT + base);
        uint4* d4 = (uint4*)rowbuf;
        for (int i = tid; i < MHALF / 4; i += 256) d4[i] = s4[i];
        __syncthreads();

        for (int j = 0; j < 7; ++j) {
            int q = tid + j * 256;
            if (q >= QTOT) break;
            float a = 0.f;
            #pragma unroll
            for (int k = 0; k < TOPK; ++k) {
                int idx = iq[(size_t)k * QTOT + q];
                if (idx >= base && idx < base + MHALF) {
                    a += wq[(size_t)k * QTOT + q] * rowbuf[idx - base];
                }
            }
            acc[j] += a;
        }
    }

    for (int j = 0; j < 7; ++j) {
        int q = tid + j * 256;
        if (q >= QTOT) break;
        out[(size_t)oc * QTOT + q] = acc[j];
    }
}

// ---------------------------------------------------------------------------
extern "C" void kernel_launch(void* const* d_in, const int* in_sizes, int n_in,
                              void* d_out, int out_size, void* d_ws, size_t ws_size,
                              hipStream_t stream) {
    const float* qk = (const float*)d_in[0];   // [64][1620] fp32
    const float* mk = (const float*)d_in[1];   // [64][32400] fp32
    const float* mv = (const float*)d_in[2];   // [1536][32400] fp32
    float* out = (float*)d_out;                // [1536][1620] fp32

    char* ws = (char*)d_ws;
    float*          asq   = (float*)(ws);                          // 129,600 B
    unsigned short* qkT   = (unsigned short*)(ws + 131072);        // 229,376 B
    unsigned short* mkT   = (unsigned short*)(ws + 360448);        // 4,147,200 B
    _Float16*       pvalh = (_Float16*)(ws + 4507648);             // 2,688,000 B
    unsigned short* pidx  = (unsigned short*)(ws + 7195648);       // 2,688,000 B
    int*            cidx  = (int*)(ws + 9883648);                  // 259,200 B
    float*          wq    = (float*)(ws + 10142848);               // 129,600 B
    int*            iq    = (int*)(ws + 10272448);                 // 129,600 B
    // total ~= 10.4 MB

    k_cast     <<<dim3((M_TOT + QPAD + 255) / 256), dim3(256), 0, stream>>>(mk, qk, mkT, qkT);
    k_asq      <<<dim3((M_TOT + 255) / 256),        dim3(256), 0, stream>>>(mk, asq);
    k_topk_mfma<<<dim3(7, NSPLIT),                  dim3(256), 0, stream>>>(mkT, qkT, asq, pvalh, pidx);
    k_merge    <<<dim3(QTOT),                       dim3(64),  0, stream>>>(pvalh, pidx, cidx);
    k_rescore  <<<dim3(QTOT),                       dim3(64),  0, stream>>>(mk, qk, asq, cidx, wq, iq);
    k_readout  <<<dim3(OCDIM),                      dim3(256), 0, stream>>>(mv, wq, iq, out);
}

// Round 4
// 542.761 us; speedup vs baseline: 2.4337x; 1.8084x over previous
//
#include <hip/hip_runtime.h>
#include <math.h>

// Problem constants (fixed by the reference; inputs confirmed fp32 in round 2)
#define M_TOT   32400
#define CKDIM   64
#define QTOT    1620
#define QPAD    1792      // 7 q-blocks x 256
#define OCDIM   1536      // O*CV = 3*512
#define TOPK    20
#define NSPLIT  75        // 32400/75 = 432 m per split
#define MSPLIT  432
#define MCHUNK  48        // 3 MFMA m-tiles; 432/48 = 9 chunks
#define KSPLIT  10        // approx top-K kept per (query, split)
#define NS      (NSPLIT*KSPLIT)   // 750 candidates per query
#define POOL    40        // approx-global pool rescored exactly
#define LDSTR   49        // aff row stride (floats): 2-way bank aliasing = free

typedef __attribute__((ext_vector_type(8))) short bf16x8;  // 8 bf16 (4 VGPRs)
typedef __attribute__((ext_vector_type(4))) float f32x4;

__device__ __forceinline__ float bf2f(unsigned short u) {
    union { unsigned int i; float f; } v;
    v.i = ((unsigned int)u) << 16;
    return v.f;
}

__device__ __forceinline__ unsigned short f2bf(float f) {
    union { float f; unsigned int i; } u;
    u.f = f;
    unsigned int r = u.i + 0x7FFF + ((u.i >> 16) & 1);  // RTNE
    return (unsigned short)(r >> 16);
}

// ---------------------------------------------------------------------------
// K_cast: build bf16 transposed copies.
//   mkT[m][c] = bf16(mk[c][m])   (32400 x 64)
//   qkT[q][c] = bf16(qk[c][q])   (1792 x 64, rows >= 1620 zeroed)
// ---------------------------------------------------------------------------
__global__ __launch_bounds__(256) void k_cast(const float* __restrict__ mk,
                                              const float* __restrict__ qk,
                                              unsigned short* __restrict__ mkT,
                                              unsigned short* __restrict__ qkT) {
    int idx = blockIdx.x * 256 + threadIdx.x;
    if (idx < M_TOT) {
        int m = idx;
        uint4* dst = (uint4*)(mkT + (size_t)m * CKDIM);
        #pragma unroll
        for (int g = 0; g < CKDIM / 8; ++g) {
            unsigned int r[4];
            #pragma unroll
            for (int p = 0; p < 4; ++p) {
                float v0 = mk[(size_t)(g * 8 + p * 2 + 0) * M_TOT + m];
                float v1 = mk[(size_t)(g * 8 + p * 2 + 1) * M_TOT + m];
                r[p] = (unsigned int)f2bf(v0) | ((unsigned int)f2bf(v1) << 16);
            }
            dst[g] = make_uint4(r[0], r[1], r[2], r[3]);
        }
    } else if (idx < M_TOT + QPAD) {
        int q = idx - M_TOT;
        uint4* dst = (uint4*)(qkT + (size_t)q * CKDIM);
        #pragma unroll
        for (int g = 0; g < CKDIM / 8; ++g) {
            unsigned int r[4];
            #pragma unroll
            for (int p = 0; p < 4; ++p) {
                float v0 = (q < QTOT) ? qk[(size_t)(g * 8 + p * 2 + 0) * QTOT + q] : 0.f;
                float v1 = (q < QTOT) ? qk[(size_t)(g * 8 + p * 2 + 1) * QTOT + q] : 0.f;
                r[p] = (unsigned int)f2bf(v0) | ((unsigned int)f2bf(v1) << 16);
            }
            dst[g] = make_uint4(r[0], r[1], r[2], r[3]);
        }
    }
}

// ---------------------------------------------------------------------------
// K0: a_sq[m] = sum_c mk[c][m]^2  (fp32 exact)
// ---------------------------------------------------------------------------
__global__ __launch_bounds__(256) void k_asq(const float* __restrict__ mk,
                                             float* __restrict__ asq) {
    int m = blockIdx.x * 256 + threadIdx.x;
    if (m >= M_TOT) return;
    float s = 0.f;
    #pragma unroll
    for (int c = 0; c < CKDIM; ++c) { float v = mk[(size_t)c * M_TOT + m]; s += v * v; }
    asq[m] = s;
}

// Branchless insert into descending-sorted top-10 (caller guards cv > tv[9]).
__device__ __forceinline__ void insert10(float (&tv)[KSPLIT], int (&ti)[KSPLIT],
                                         float cv, int ci) {
    #pragma unroll
    for (int j = KSPLIT - 1; j >= 1; --j) {
        bool sj = tv[j] >= cv;
        bool sp = tv[j - 1] >= cv;
        float nv = sj ? tv[j] : (sp ? cv : tv[j - 1]);
        int   ni = sj ? ti[j] : (sp ? ci : ti[j - 1]);
        tv[j] = nv; ti[j] = ni;
    }
    bool s0 = tv[0] >= cv;
    float nv0 = s0 ? tv[0] : cv;
    int   ni0 = s0 ? ti[0] : ci;
    tv[0] = nv0; ti[0] = ni0;
}

// ---------------------------------------------------------------------------
// K1: MFMA approx affinity + per-(query,split) top-10.
// grid = (7, 75); block = 256 = 4 fully independent waves (no barriers).
// Score = dot(mk_m, qk_q) - 0.5*asq[m]  (monotone transform of affinity).
// ---------------------------------------------------------------------------
__global__ __launch_bounds__(256) void k_topk_mfma(const unsigned short* __restrict__ mkT,
                                                   const unsigned short* __restrict__ qkT,
                                                   const float* __restrict__ asq,
                                                   _Float16* __restrict__ pvalh,
                                                   unsigned short* __restrict__ pidx) {
    __shared__ float aff[256 * LDSTR];   // 50,176 B
    const int tid  = threadIdx.x;
    const int lane = tid & 63;
    const int w    = tid >> 6;
    const int l15  = lane & 15;
    const int quad = lane >> 4;
    const int q0   = blockIdx.x * 256;
    const int sp   = blockIdx.y;
    const int m_base = sp * MSPLIT;

    // B-frags (qk side) — loop-invariant, kept in registers.
    bf16x8 bF[4][2];
    #pragma unroll
    for (int qt = 0; qt < 4; ++qt) {
        const unsigned short* p = qkT + (size_t)(q0 + w * 64 + qt * 16 + l15) * CKDIM + quad * 8;
        bF[qt][0] = *(const bf16x8*)(p);
        bF[qt][1] = *(const bf16x8*)(p + 32);
    }

    float tv[KSPLIT];
    int   ti[KSPLIT];
    #pragma unroll
    for (int j = 0; j < KSPLIT; ++j) { tv[j] = -INFINITY; ti[j] = 0; }

    for (int ch = 0; ch < MSPLIT / MCHUNK; ++ch) {
        const int m0 = m_base + ch * MCHUNK;
        #pragma unroll
        for (int mt = 0; mt < 3; ++mt) {
            const int mrow = m0 + mt * 16;
            f32x4 aq = *(const f32x4*)(asq + mrow + quad * 4);
            f32x4 cinit = -0.5f * aq;
            const unsigned short* pa = mkT + (size_t)(mrow + l15) * CKDIM + quad * 8;
            bf16x8 aF0 = *(const bf16x8*)(pa);
            bf16x8 aF1 = *(const bf16x8*)(pa + 32);
            #pragma unroll
            for (int qt = 0; qt < 4; ++qt) {
                f32x4 c = cinit;
                c = __builtin_amdgcn_mfma_f32_16x16x32_bf16(aF0, bF[qt][0], c, 0, 0, 0);
                c = __builtin_amdgcn_mfma_f32_16x16x32_bf16(aF1, bF[qt][1], c, 0, 0, 0);
                float* dst = &aff[(w * 64 + qt * 16 + l15) * LDSTR + mt * 16 + quad * 4];
                dst[0] = c[0]; dst[1] = c[1]; dst[2] = c[2]; dst[3] = c[3];
            }
        }
        const float* row = &aff[tid * LDSTR];
        #pragma unroll 8
        for (int m = 0; m < MCHUNK; ++m) {
            float v = row[m];
            if (v > tv[KSPLIT - 1]) insert10(tv, ti, v, m0 + m);
        }
    }

    _Float16*       pv = pvalh + (size_t)(q0 + tid) * NS + sp * KSPLIT;
    unsigned short* pi = pidx  + (size_t)(q0 + tid) * NS + sp * KSPLIT;
    #pragma unroll
    for (int j = 0; j < KSPLIT; ++j) {
        pv[j] = (_Float16)tv[j];
        pi[j] = (unsigned short)ti[j];
    }
}

// ---------------------------------------------------------------------------
// K2: per query, approx-global top-40 candidate pool (indices only).
// ---------------------------------------------------------------------------
__global__ __launch_bounds__(64) void k_merge(const _Float16* __restrict__ pvalh,
                                              const unsigned short* __restrict__ pidx,
                                              int* __restrict__ cidx) {
    const int q    = blockIdx.x;
    const int lane = threadIdx.x;
    __shared__ float sv[NS];
    __shared__ int   si[NS];

    for (int s = lane; s < NS; s += 64) {
        sv[s] = (float)pvalh[(size_t)q * NS + s];
        si[s] = (int)pidx[(size_t)q * NS + s];
    }
    __syncthreads();

    for (int r = 0; r < POOL; ++r) {
        float bv = -INFINITY;
        int   bs = NS;
        #pragma unroll
        for (int it = 0; it < (NS + 63) / 64; ++it) {
            int s = lane + it * 64;
            if (s < NS) {
                float v = sv[s];
                if (v > bv) { bv = v; bs = s; }
            }
        }
        #pragma unroll
        for (int off = 32; off; off >>= 1) {
            float ov = __shfl_xor(bv, off);
            int   os = __shfl_xor(bs, off);
            if (ov > bv || (ov == bv && os < bs)) { bv = ov; bs = os; }
        }
        if (lane == 0) {
            cidx[(size_t)q * POOL + r] = si[bs];
            sv[bs] = -INFINITY;
        }
        __syncthreads();
    }
}

// ---------------------------------------------------------------------------
// K3: exact fp32 rescore of the 40-candidate pool; exact top-20 + softmax.
// Output packed per query: qw[q][k] = {idx, w_bits} (uint2).
// ---------------------------------------------------------------------------
__global__ __launch_bounds__(64) void k_rescore(const float* __restrict__ mk,
                                                const float* __restrict__ qk,
                                                const float* __restrict__ asq,
                                                const int* __restrict__ cidx,
                                                uint2* __restrict__ qw) {
    const int q    = blockIdx.x;
    const int lane = threadIdx.x;
    const int m_l  = (lane < POOL) ? cidx[(size_t)q * POOL + lane] : 0;

    float dot = 0.f;
    #pragma unroll
    for (int c = 0; c < CKDIM; ++c)
        dot += mk[(size_t)c * M_TOT + m_l] * qk[(size_t)c * QTOT + q];
    float aff = (lane < POOL) ? (2.f * dot - asq[m_l]) * 0.125f : -INFINITY;

    __shared__ float kv[TOPK];
    __shared__ int   ki[TOPK];

    for (int r = 0; r < TOPK; ++r) {
        float bv = aff;
        int   bm = m_l;
        #pragma unroll
        for (int off = 32; off; off >>= 1) {
            float ov = __shfl_xor(bv, off);
            int   om = __shfl_xor(bm, off);
            if (ov > bv || (ov == bv && om < bm)) { bv = ov; bm = om; }
        }
        if (aff == bv && m_l == bm) aff = -INFINITY;   // deactivate winner (m unique)
        if (lane == 0) { kv[r] = bv; ki[r] = bm; }
    }
    __syncthreads();

    float e = (lane < TOPK) ? __expf(kv[lane] - kv[0]) : 0.f;
    float sum = e;
    #pragma unroll
    for (int off = 32; off; off >>= 1) sum += __shfl_xor(sum, off);

    if (lane < TOPK) {
        unsigned int wbits;
        { union { float f; unsigned int i; } u; u.f = e / sum; wbits = u.i; }
        qw[(size_t)q * TOPK + lane] = make_uint2((unsigned int)ki[lane], wbits);
    }
}

// ---------------------------------------------------------------------------
// K4: readout v3. Block (512 thr) per oc row. Stage V row as bf16 in LDS
// (64.8 KB, single pass): 15 fixed-trip uint4 loads into registers first
// (deep MLP), then convert+write. Compute: packed 160 B/lane weight reads,
// 20 LDS gathers, scalar acc, immediate store. No spills: ~90 VGPR.
// ---------------------------------------------------------------------------
__global__ __launch_bounds__(512, 4) void k_readout(const float* __restrict__ mv,
                                                    const uint2* __restrict__ qw,
                                                    float* __restrict__ out) {
    __shared__ unsigned short row[M_TOT];   // 64,800 B
    const int oc  = blockIdx.x;
    const int tid = threadIdx.x;

    // ---- stage: 8100 uint4 chunks = 32400 floats -> bf16 LDS ----
    const uint4* s4 = (const uint4*)(mv + (size_t)oc * M_TOT);
    uint4 tmp[15];
    #pragma unroll
    for (int it = 0; it < 15; ++it) tmp[it] = s4[tid + it * 512];   // 15 loads in flight
    uint4 tail;
    const int ti_idx = 15 * 512 + tid;   // 7680 + tid
    if (tid < M_TOT / 4 - 15 * 512)      // tid < 420
        tail = s4[ti_idx];

    ushort4* d4 = (ushort4*)row;
    #pragma unroll
    for (int it = 0; it < 15; ++it) {
        uint4 v = tmp[it];
        ushort4 h;
        h.x = f2bf(__uint_as_float(v.x));
        h.y = f2bf(__uint_as_float(v.y));
        h.z = f2bf(__uint_as_float(v.z));
        h.w = f2bf(__uint_as_float(v.w));
        d4[tid + it * 512] = h;
    }
    if (tid < M_TOT / 4 - 15 * 512) {
        ushort4 h;
        h.x = f2bf(__uint_as_float(tail.x));
        h.y = f2bf(__uint_as_float(tail.y));
        h.z = f2bf(__uint_as_float(tail.z));
        h.w = f2bf(__uint_as_float(tail.w));
        d4[ti_idx] = h;
    }
    __syncthreads();

    // ---- compute: q = tid, tid+512, tid+1024, (+1536 for tid<84) ----
    #pragma unroll
    for (int j = 0; j < 4; ++j) {
        int q = tid + j * 512;
        if (q >= QTOT) break;
        const uint2* p = qw + (size_t)q * TOPK;
        float acc = 0.f;
        #pragma unroll
        for (int k = 0; k < TOPK; ++k) {
            uint2 e = p[k];
            acc += __uint_as_float(e.y) * bf2f(row[e.x]);
        }
        out[(size_t)oc * QTOT + q] = acc;
    }
}

// ---------------------------------------------------------------------------
extern "C" void kernel_launch(void* const* d_in, const int* in_sizes, int n_in,
                              void* d_out, int out_size, void* d_ws, size_t ws_size,
                              hipStream_t stream) {
    const float* qk = (const float*)d_in[0];   // [64][1620] fp32
    const float* mk = (const float*)d_in[1];   // [64][32400] fp32
    const float* mv = (const float*)d_in[2];   // [1536][32400] fp32
    float* out = (float*)d_out;                // [1536][1620] fp32

    char* ws = (char*)d_ws;
    float*          asq   = (float*)(ws);                          // 129,600 B
    unsigned short* qkT   = (unsigned short*)(ws + 131072);        // 229,376 B
    unsigned short* mkT   = (unsigned short*)(ws + 360448);        // 4,147,200 B
    _Float16*       pvalh = (_Float16*)(ws + 4507648);             // 2,688,000 B
    unsigned short* pidx  = (unsigned short*)(ws + 7195648);       // 2,688,000 B
    int*            cidx  = (int*)(ws + 9883648);                  // 259,200 B
    uint2*          qw    = (uint2*)(ws + 10142848);               // 259,200 B
    // total ~= 10.4 MB

    k_cast     <<<dim3((M_TOT + QPAD + 255) / 256), dim3(256), 0, stream>>>(mk, qk, mkT, qkT);
    k_asq      <<<dim3((M_TOT + 255) / 256),        dim3(256), 0, stream>>>(mk, asq);
    k_topk_mfma<<<dim3(7, NSPLIT),                  dim3(256), 0, stream>>>(mkT, qkT, asq, pvalh, pidx);
    k_merge    <<<dim3(QTOT),                       dim3(64),  0, stream>>>(pvalh, pidx, cidx);
    k_rescore  <<<dim3(QTOT),                       dim3(64),  0, stream>>>(mk, qk, asq, cidx, qw);
    k_readout  <<<dim3(OCDIM),                      dim3(512), 0, stream>>>(mv, qw, out);
}

// Round 5
// 387.457 us; speedup vs baseline: 3.4092x; 1.4008x over previous
//
#include <hip/hip_runtime.h>
#include <math.h>

// Problem constants (fixed by the reference; inputs are fp32)
#define M_TOT   32400
#define CKDIM   64
#define QTOT    1620
#define QPAD    1792      // 28 q-groups x 64
#define OCDIM   1536      // O*CV = 3*512
#define TOPK    20
#define NSPLIT  45        // 32400/45 = 720 m per split
#define MSPLIT  720
#define NCHUNK  15        // 15 chunks x 48 m
#define KSPLIT  20        // 4 quads x 5 keys per (q, split)
#define KEYSQ   (NSPLIT*KSPLIT)   // 900 keys per query
#define POOL    32        // approx-global pool rescored exactly

typedef __attribute__((ext_vector_type(8))) short bf16x8;  // 8 bf16 (4 VGPRs)
typedef __attribute__((ext_vector_type(4))) float f32x4;

__device__ __forceinline__ float bf2f(unsigned short u) {
    union { unsigned int i; float f; } v;
    v.i = ((unsigned int)u) << 16;
    return v.f;
}

__device__ __forceinline__ unsigned short f2bf(float f) {
    union { float f; unsigned int i; } u;
    u.f = f;
    unsigned int r = u.i + 0x7FFF + ((u.i >> 16) & 1);  // RTNE
    return (unsigned short)(r >> 16);
}

__device__ __forceinline__ float med3f(float a, float b, float c) {
#if __has_builtin(__builtin_amdgcn_fmed3f)
    return __builtin_amdgcn_fmed3f(a, b, c);
#else
    return fmaxf(fminf(a, b), fminf(fmaxf(a, b), c));
#endif
}

// Branch-free insert of x into descending-sorted 5-list (med3 chain).
#define INS5(t, x) do {                    \
    t[4] = med3f((x), t[3], t[4]);         \
    t[3] = med3f((x), t[2], t[3]);         \
    t[2] = med3f((x), t[1], t[2]);         \
    t[1] = med3f((x), t[0], t[1]);         \
    t[0] = fmaxf(t[0], (x));               \
} while (0)

#define INS8(t, x) do {                    \
    t[7] = med3f((x), t[6], t[7]);         \
    t[6] = med3f((x), t[5], t[6]);         \
    t[5] = med3f((x), t[4], t[5]);         \
    t[4] = med3f((x), t[3], t[4]);         \
    t[3] = med3f((x), t[2], t[3]);         \
    t[2] = med3f((x), t[1], t[2]);         \
    t[1] = med3f((x), t[0], t[1]);         \
    t[0] = fmaxf(t[0], (x));               \
} while (0)

// ---------------------------------------------------------------------------
// K_cast: bf16 transposed copies. mkT[m][c], qkT[q][c] (c contiguous).
// ---------------------------------------------------------------------------
__global__ __launch_bounds__(256) void k_cast(const float* __restrict__ mk,
                                              const float* __restrict__ qk,
                                              unsigned short* __restrict__ mkT,
                                              unsigned short* __restrict__ qkT) {
    int idx = blockIdx.x * 256 + threadIdx.x;
    if (idx < M_TOT) {
        int m = idx;
        uint4* dst = (uint4*)(mkT + (size_t)m * CKDIM);
        #pragma unroll
        for (int g = 0; g < CKDIM / 8; ++g) {
            unsigned int r[4];
            #pragma unroll
            for (int p = 0; p < 4; ++p) {
                float v0 = mk[(size_t)(g * 8 + p * 2 + 0) * M_TOT + m];
                float v1 = mk[(size_t)(g * 8 + p * 2 + 1) * M_TOT + m];
                r[p] = (unsigned int)f2bf(v0) | ((unsigned int)f2bf(v1) << 16);
            }
            dst[g] = make_uint4(r[0], r[1], r[2], r[3]);
        }
    } else if (idx < M_TOT + QPAD) {
        int q = idx - M_TOT;
        uint4* dst = (uint4*)(qkT + (size_t)q * CKDIM);
        #pragma unroll
        for (int g = 0; g < CKDIM / 8; ++g) {
            unsigned int r[4];
            #pragma unroll
            for (int p = 0; p < 4; ++p) {
                float v0 = (q < QTOT) ? qk[(size_t)(g * 8 + p * 2 + 0) * QTOT + q] : 0.f;
                float v1 = (q < QTOT) ? qk[(size_t)(g * 8 + p * 2 + 1) * QTOT + q] : 0.f;
                r[p] = (unsigned int)f2bf(v0) | ((unsigned int)f2bf(v1) << 16);
            }
            dst[g] = make_uint4(r[0], r[1], r[2], r[3]);
        }
    }
}

// ---------------------------------------------------------------------------
// K0: a_sq[m] = sum_c mk[c][m]^2  (fp32 exact)
// ---------------------------------------------------------------------------
__global__ __launch_bounds__(256) void k_asq(const float* __restrict__ mk,
                                             float* __restrict__ asq) {
    int m = blockIdx.x * 256 + threadIdx.x;
    if (m >= M_TOT) return;
    float s = 0.f;
    #pragma unroll
    for (int c = 0; c < CKDIM; ++c) { float v = mk[(size_t)c * M_TOT + m]; s += v * v; }
    asq[m] = s;
}

// ---------------------------------------------------------------------------
// K1: MFMA affinity scan, selection fully in registers on packed keys.
// grid = (28 q-groups, 45 splits), block = 1 wave (64 lanes).
// Score = dot - 0.5*asq (monotone in affinity); key = (score & ~0x7FFF) | m.
// Each lane: q-col = qt*16+l15, keeps top-5 per (qt, its m-quarter) via med3.
// C/D layout (verified r3/r4): col=lane&15 (q), row=quad*4+reg (m).
// ---------------------------------------------------------------------------
__global__ __launch_bounds__(64) void k_topk_mfma(const unsigned short* __restrict__ mkT,
                                                  const unsigned short* __restrict__ qkT,
                                                  const float* __restrict__ asq,
                                                  float* __restrict__ pkeys) {
    const int lane = threadIdx.x;
    const int l15  = lane & 15;
    const int quad = lane >> 4;
    const int q_base = blockIdx.x * 64;
    const int sp     = blockIdx.y;
    const int m_base = sp * MSPLIT;

    // B-frags (qk side) — loop-invariant.
    bf16x8 bF[4][2];
    #pragma unroll
    for (int qt = 0; qt < 4; ++qt) {
        const unsigned short* p = qkT + (size_t)(q_base + qt * 16 + l15) * CKDIM + quad * 8;
        bF[qt][0] = *(const bf16x8*)(p);
        bF[qt][1] = *(const bf16x8*)(p + 32);
    }

    float key5[4][5];
    #pragma unroll
    for (int qt = 0; qt < 4; ++qt)
        #pragma unroll
        for (int j = 0; j < 5; ++j) key5[qt][j] = -INFINITY;

    for (int ch = 0; ch < NCHUNK; ++ch) {
        #pragma unroll
        for (int mt = 0; mt < 3; ++mt) {
            const int mrow = m_base + ch * 48 + mt * 16;
            f32x4 aq = *(const f32x4*)(asq + mrow + quad * 4);
            f32x4 cinit = -0.5f * aq;
            const unsigned short* pa = mkT + (size_t)(mrow + l15) * CKDIM + quad * 8;
            bf16x8 aF0 = *(const bf16x8*)(pa);
            bf16x8 aF1 = *(const bf16x8*)(pa + 32);
            const unsigned int mq = (unsigned int)(mrow + quad * 4);
            #pragma unroll
            for (int qt = 0; qt < 4; ++qt) {
                f32x4 c = cinit;
                c = __builtin_amdgcn_mfma_f32_16x16x32_bf16(aF0, bF[qt][0], c, 0, 0, 0);
                c = __builtin_amdgcn_mfma_f32_16x16x32_bf16(aF1, bF[qt][1], c, 0, 0, 0);
                #pragma unroll
                for (int i = 0; i < 4; ++i) {
                    unsigned int kb = (__float_as_uint(c[i]) & 0xFFFF8000u) | (mq + i);
                    float kf = __uint_as_float(kb);
                    INS5(key5[qt], kf);
                }
            }
        }
    }

    // Write 4 quads x 5 keys per (q, split).
    #pragma unroll
    for (int qt = 0; qt < 4; ++qt) {
        const int q = q_base + qt * 16 + l15;
        float* dst = pkeys + (size_t)q * KEYSQ + sp * KSPLIT + quad * 5;
        #pragma unroll
        for (int j = 0; j < 5; ++j) dst[j] = key5[qt][j];
    }
}

// ---------------------------------------------------------------------------
// K2: fused select. One wave per query:
//  (a) lane-local sorted top-8 over strided 900 keys,
//  (b) 32-round tournament pop -> pool (register-resident, lane r holds r-th),
//  (c) exact fp32 rescore of pool, exact top-20 + softmax -> packed qw.
// Keys are globally unique per query (index embedded) -> no tie handling.
// ---------------------------------------------------------------------------
__global__ __launch_bounds__(64) void k_select(const float* __restrict__ pkeys,
                                               const float* __restrict__ mk,
                                               const float* __restrict__ qk,
                                               const float* __restrict__ asq,
                                               uint2* __restrict__ qw) {
    const int q    = blockIdx.x;
    const int lane = threadIdx.x;

    // (a) local top-8
    float t[8];
    #pragma unroll
    for (int j = 0; j < 8; ++j) t[j] = -INFINITY;
    const float* src = pkeys + (size_t)q * KEYSQ;
    #pragma unroll
    for (int i = 0; i < 15; ++i) {
        int s = lane + i * 64;
        float v = (s < KEYSQ) ? src[s] : -INFINITY;
        INS8(t, v);
    }

    // (b) tournament: pop global max 32 times
    float mykey = -INFINITY;
    for (int r = 0; r < POOL; ++r) {
        float h = t[0];
        float wm = h;
        #pragma unroll
        for (int off = 32; off; off >>= 1) wm = fmaxf(wm, __shfl_xor(wm, off));
        bool win = (h == wm);
        t[0] = win ? t[1] : t[0];
        t[1] = win ? t[2] : t[1];
        t[2] = win ? t[3] : t[2];
        t[3] = win ? t[4] : t[3];
        t[4] = win ? t[5] : t[4];
        t[5] = win ? t[6] : t[5];
        t[6] = win ? t[7] : t[6];
        t[7] = win ? -INFINITY : t[7];
        if (lane == r) mykey = wm;
    }

    // (c) exact rescore: lane < POOL owns candidate m = low 15 bits of key
    const int  m_l = (int)(__float_as_uint(mykey) & 0x7FFFu);
    const bool act = (lane < POOL);

    float dot = 0.f;
    #pragma unroll
    for (int c = 0; c < CKDIM; ++c)
        dot += mk[(size_t)c * M_TOT + m_l] * qk[(size_t)c * QTOT + q];
    float aff = act ? (2.f * dot - asq[m_l]) * 0.125f : -INFINITY;

    __shared__ float kv[TOPK];
    __shared__ int   ki[TOPK];

    for (int r = 0; r < TOPK; ++r) {
        float bv = aff;
        int   bm = m_l;
        #pragma unroll
        for (int off = 32; off; off >>= 1) {
            float ov = __shfl_xor(bv, off);
            int   om = __shfl_xor(bm, off);
            if (ov > bv || (ov == bv && om < bm)) { bv = ov; bm = om; }
        }
        if (aff == bv && m_l == bm) aff = -INFINITY;   // deactivate winner (m unique)
        if (lane == 0) { kv[r] = bv; ki[r] = bm; }
    }
    __syncthreads();

    float e = (lane < TOPK) ? __expf(kv[lane] - kv[0]) : 0.f;
    float sum = e;
    #pragma unroll
    for (int off = 32; off; off >>= 1) sum += __shfl_xor(sum, off);

    if (lane < TOPK) {
        unsigned int wbits;
        { union { float f; unsigned int i; } u; u.f = e / sum; wbits = u.i; }
        qw[(size_t)q * TOPK + lane] = make_uint2((unsigned int)ki[lane], wbits);
    }
}

// ---------------------------------------------------------------------------
// K3: readout (proven in r4). Block (512 thr) per oc row; V row bf16 in LDS.
// ---------------------------------------------------------------------------
__global__ __launch_bounds__(512, 4) void k_readout(const float* __restrict__ mv,
                                                    const uint2* __restrict__ qw,
                                                    float* __restrict__ out) {
    __shared__ unsigned short row[M_TOT];   // 64,800 B
    const int oc  = blockIdx.x;
    const int tid = threadIdx.x;

    const uint4* s4 = (const uint4*)(mv + (size_t)oc * M_TOT);
    uint4 tmp[15];
    #pragma unroll
    for (int it = 0; it < 15; ++it) tmp[it] = s4[tid + it * 512];
    uint4 tail;
    const int ti_idx = 15 * 512 + tid;
    if (tid < M_TOT / 4 - 15 * 512)
        tail = s4[ti_idx];

    ushort4* d4 = (ushort4*)row;
    #pragma unroll
    for (int it = 0; it < 15; ++it) {
        uint4 v = tmp[it];
        ushort4 h;
        h.x = f2bf(__uint_as_float(v.x));
        h.y = f2bf(__uint_as_float(v.y));
        h.z = f2bf(__uint_as_float(v.z));
        h.w = f2bf(__uint_as_float(v.w));
        d4[tid + it * 512] = h;
    }
    if (tid < M_TOT / 4 - 15 * 512) {
        ushort4 h;
        h.x = f2bf(__uint_as_float(tail.x));
        h.y = f2bf(__uint_as_float(tail.y));
        h.z = f2bf(__uint_as_float(tail.z));
        h.w = f2bf(__uint_as_float(tail.w));
        d4[ti_idx] = h;
    }
    __syncthreads();

    #pragma unroll
    for (int j = 0; j < 4; ++j) {
        int q = tid + j * 512;
        if (q >= QTOT) break;
        const uint2* p = qw + (size_t)q * TOPK;
        float acc = 0.f;
        #pragma unroll
        for (int k = 0; k < TOPK; ++k) {
            uint2 e = p[k];
            acc += __uint_as_float(e.y) * bf2f(row[e.x]);
        }
        out[(size_t)oc * QTOT + q] = acc;
    }
}

// ---------------------------------------------------------------------------
extern "C" void kernel_launch(void* const* d_in, const int* in_sizes, int n_in,
                              void* d_out, int out_size, void* d_ws, size_t ws_size,
                              hipStream_t stream) {
    const float* qk = (const float*)d_in[0];   // [64][1620] fp32
    const float* mk = (const float*)d_in[1];   // [64][32400] fp32
    const float* mv = (const float*)d_in[2];   // [1536][32400] fp32
    float* out = (float*)d_out;                // [1536][1620] fp32

    char* ws = (char*)d_ws;
    float*          asq   = (float*)(ws);                      // 129,600 B
    unsigned short* qkT   = (unsigned short*)(ws + 131072);    // 229,376 B
    unsigned short* mkT   = (unsigned short*)(ws + 360448);    // 4,147,200 B
    float*          pkeys = (float*)(ws + 4507648);            // 1792*900*4 = 6,451,200 B
    uint2*          qw    = (uint2*)(ws + 10958848);           // 259,200 B
    // total ~= 11.2 MB

    k_cast     <<<dim3((M_TOT + QPAD + 255) / 256), dim3(256), 0, stream>>>(mk, qk, mkT, qkT);
    k_asq      <<<dim3((M_TOT + 255) / 256),        dim3(256), 0, stream>>>(mk, asq);
    k_topk_mfma<<<dim3(28, NSPLIT),                 dim3(64),  0, stream>>>(mkT, qkT, asq, pkeys);
    k_select   <<<dim3(QTOT),                       dim3(64),  0, stream>>>(pkeys, mk, qk, asq, qw);
    k_readout  <<<dim3(OCDIM),                      dim3(512), 0, stream>>>(mv, qw, out);
}

// Round 6
// 369.902 us; speedup vs baseline: 3.5710x; 1.0475x over previous
//
#include <hip/hip_runtime.h>
#include <math.h>

// Problem constants (fixed by the reference; inputs are fp32)
#define M_TOT   32400
#define CKDIM   64
#define QTOT    1620
#define QPAD    1792      // 28 q-groups x 64
#define OCDIM   1536      // O*CV = 3*512
#define TOPK    20
#define NSPLIT  45        // 32400/45 = 720 m per split
#define MSPLIT  720
#define NCHUNK  15        // 15 chunks x 48 m
#define KSPLIT  20        // 4 quads x 5 keys per (q, split)
#define KEYSQ   (NSPLIT*KSPLIT)   // 900 keys per query
#define POOL    32        // approx-global pool rescored exactly

typedef __attribute__((ext_vector_type(8))) short bf16x8;  // 8 bf16 (4 VGPRs)
typedef __attribute__((ext_vector_type(4))) float f32x4;

__device__ __forceinline__ float bf2f(unsigned short u) {
    union { unsigned int i; float f; } v;
    v.i = ((unsigned int)u) << 16;
    return v.f;
}

__device__ __forceinline__ unsigned short f2bf(float f) {
    union { float f; unsigned int i; } u;
    u.f = f;
    unsigned int r = u.i + 0x7FFF + ((u.i >> 16) & 1);  // RTNE
    return (unsigned short)(r >> 16);
}

__device__ __forceinline__ float med3f(float a, float b, float c) {
#if __has_builtin(__builtin_amdgcn_fmed3f)
    return __builtin_amdgcn_fmed3f(a, b, c);
#else
    return fmaxf(fminf(a, b), fminf(fmaxf(a, b), c));
#endif
}

// Branch-free insert of x into descending-sorted 5-list (med3 chain).
#define INS5(t, x) do {                    \
    t[4] = med3f((x), t[3], t[4]);         \
    t[3] = med3f((x), t[2], t[3]);         \
    t[2] = med3f((x), t[1], t[2]);         \
    t[1] = med3f((x), t[0], t[1]);         \
    t[0] = fmaxf(t[0], (x));               \
} while (0)

#define INS8(t, x) do {                    \
    t[7] = med3f((x), t[6], t[7]);         \
    t[6] = med3f((x), t[5], t[6]);         \
    t[5] = med3f((x), t[4], t[5]);         \
    t[4] = med3f((x), t[3], t[4]);         \
    t[3] = med3f((x), t[2], t[3]);         \
    t[2] = med3f((x), t[1], t[2]);         \
    t[1] = med3f((x), t[0], t[1]);         \
    t[0] = fmaxf(t[0], (x));               \
} while (0)

// ---------------------------------------------------------------------------
// K_prep: single pass over mk (and qk) producing:
//   asq[m]      = sum_c mk[c][m]^2            (fp32 exact)
//   mkT[m][c]   = bf16(mk[c][m])              (MFMA A-side)
//   mkTf[m][c]  = mk[c][m]                    (fp32, contiguous rescore rows)
//   qkT[q][c]   = bf16(qk[c][q])  (QPAD rows, zero-padded)
//   qkTf[q][c]  = qk[c][q]        (QPAD rows, zero-padded)
// ---------------------------------------------------------------------------
__global__ __launch_bounds__(256) void k_prep(const float* __restrict__ mk,
                                              const float* __restrict__ qk,
                                              float* __restrict__ asq,
                                              unsigned short* __restrict__ mkT,
                                              float* __restrict__ mkTf,
                                              unsigned short* __restrict__ qkT,
                                              float* __restrict__ qkTf) {
    int idx = blockIdx.x * 256 + threadIdx.x;
    if (idx < M_TOT) {
        const int m = idx;
        float vals[CKDIM];
        float s = 0.f;
        #pragma unroll
        for (int c = 0; c < CKDIM; ++c) {
            vals[c] = mk[(size_t)c * M_TOT + m];
            s += vals[c] * vals[c];
        }
        asq[m] = s;
        uint4* db = (uint4*)(mkT + (size_t)m * CKDIM);
        #pragma unroll
        for (int g = 0; g < 8; ++g) {
            unsigned int r[4];
            #pragma unroll
            for (int p = 0; p < 4; ++p)
                r[p] = (unsigned int)f2bf(vals[g * 8 + 2 * p])
                     | ((unsigned int)f2bf(vals[g * 8 + 2 * p + 1]) << 16);
            db[g] = make_uint4(r[0], r[1], r[2], r[3]);
        }
        float4* df = (float4*)(mkTf + (size_t)m * CKDIM);
        #pragma unroll
        for (int g = 0; g < 16; ++g)
            df[g] = make_float4(vals[4 * g], vals[4 * g + 1], vals[4 * g + 2], vals[4 * g + 3]);
    } else if (idx < M_TOT + QPAD) {
        const int q = idx - M_TOT;
        float vals[CKDIM];
        #pragma unroll
        for (int c = 0; c < CKDIM; ++c)
            vals[c] = (q < QTOT) ? qk[(size_t)c * QTOT + q] : 0.f;
        uint4* db = (uint4*)(qkT + (size_t)q * CKDIM);
        #pragma unroll
        for (int g = 0; g < 8; ++g) {
            unsigned int r[4];
            #pragma unroll
            for (int p = 0; p < 4; ++p)
                r[p] = (unsigned int)f2bf(vals[g * 8 + 2 * p])
                     | ((unsigned int)f2bf(vals[g * 8 + 2 * p + 1]) << 16);
            db[g] = make_uint4(r[0], r[1], r[2], r[3]);
        }
        float4* df = (float4*)(qkTf + (size_t)q * CKDIM);
        #pragma unroll
        for (int g = 0; g < 16; ++g)
            df[g] = make_float4(vals[4 * g], vals[4 * g + 1], vals[4 * g + 2], vals[4 * g + 3]);
    }
}

// ---------------------------------------------------------------------------
// K1: MFMA affinity scan, selection fully in registers on packed keys.
// grid = (28 q-groups, 45 splits), block = 1 wave.
// Score = dot - 0.5*asq (monotone in affinity); key = (score & ~0x7FFF) | m.
// C/D layout (verified r3-r5): col=lane&15 (q), row=quad*4+reg (m).
// ---------------------------------------------------------------------------
__global__ __launch_bounds__(64) void k_topk_mfma(const unsigned short* __restrict__ mkT,
                                                  const unsigned short* __restrict__ qkT,
                                                  const float* __restrict__ asq,
                                                  float* __restrict__ pkeys) {
    const int lane = threadIdx.x;
    const int l15  = lane & 15;
    const int quad = lane >> 4;
    const int q_base = blockIdx.x * 64;
    const int sp     = blockIdx.y;
    const int m_base = sp * MSPLIT;

    bf16x8 bF[4][2];
    #pragma unroll
    for (int qt = 0; qt < 4; ++qt) {
        const unsigned short* p = qkT + (size_t)(q_base + qt * 16 + l15) * CKDIM + quad * 8;
        bF[qt][0] = *(const bf16x8*)(p);
        bF[qt][1] = *(const bf16x8*)(p + 32);
    }

    float key5[4][5];
    #pragma unroll
    for (int qt = 0; qt < 4; ++qt)
        #pragma unroll
        for (int j = 0; j < 5; ++j) key5[qt][j] = -INFINITY;

    for (int ch = 0; ch < NCHUNK; ++ch) {
        #pragma unroll
        for (int mt = 0; mt < 3; ++mt) {
            const int mrow = m_base + ch * 48 + mt * 16;
            f32x4 aq = *(const f32x4*)(asq + mrow + quad * 4);
            f32x4 cinit = -0.5f * aq;
            const unsigned short* pa = mkT + (size_t)(mrow + l15) * CKDIM + quad * 8;
            bf16x8 aF0 = *(const bf16x8*)(pa);
            bf16x8 aF1 = *(const bf16x8*)(pa + 32);
            const unsigned int mq = (unsigned int)(mrow + quad * 4);
            #pragma unroll
            for (int qt = 0; qt < 4; ++qt) {
                f32x4 c = cinit;
                c = __builtin_amdgcn_mfma_f32_16x16x32_bf16(aF0, bF[qt][0], c, 0, 0, 0);
                c = __builtin_amdgcn_mfma_f32_16x16x32_bf16(aF1, bF[qt][1], c, 0, 0, 0);
                #pragma unroll
                for (int i = 0; i < 4; ++i) {
                    unsigned int kb = (__float_as_uint(c[i]) & 0xFFFF8000u) | (mq + i);
                    float kf = __uint_as_float(kb);
                    INS5(key5[qt], kf);
                }
            }
        }
    }

    #pragma unroll
    for (int qt = 0; qt < 4; ++qt) {
        const int q = q_base + qt * 16 + l15;
        float* dst = pkeys + (size_t)q * KEYSQ + sp * KSPLIT + quad * 5;
        #pragma unroll
        for (int j = 0; j < 5; ++j) dst[j] = key5[qt][j];
    }
}

// ---------------------------------------------------------------------------
// K2: fused select. One wave per query:
//  (a) lane-local sorted top-8 over strided 900 keys,
//  (b) 32-round tournament pop -> register-resident pool,
//  (c) exact fp32 rescore using CONTIGUOUS mkTf rows, top-20 + softmax.
// ---------------------------------------------------------------------------
__global__ __launch_bounds__(64) void k_select(const float* __restrict__ pkeys,
                                               const float* __restrict__ mkTf,
                                               const float* __restrict__ qkTf,
                                               const float* __restrict__ asq,
                                               uint2* __restrict__ qw) {
    const int q    = blockIdx.x;
    const int lane = threadIdx.x;

    // (a) local top-8
    float t[8];
    #pragma unroll
    for (int j = 0; j < 8; ++j) t[j] = -INFINITY;
    const float* src = pkeys + (size_t)q * KEYSQ;
    #pragma unroll
    for (int i = 0; i < 15; ++i) {
        int s = lane + i * 64;
        float v = (s < KEYSQ) ? src[s] : -INFINITY;
        INS8(t, v);
    }

    // (b) tournament: pop global max 32 times
    float mykey = -INFINITY;
    for (int r = 0; r < POOL; ++r) {
        float h = t[0];
        float wm = h;
        #pragma unroll
        for (int off = 32; off; off >>= 1) wm = fmaxf(wm, __shfl_xor(wm, off));
        bool win = (h == wm);
        t[0] = win ? t[1] : t[0];
        t[1] = win ? t[2] : t[1];
        t[2] = win ? t[3] : t[2];
        t[3] = win ? t[4] : t[3];
        t[4] = win ? t[5] : t[4];
        t[5] = win ? t[6] : t[5];
        t[6] = win ? t[7] : t[6];
        t[7] = win ? -INFINITY : t[7];
        if (lane == r) mykey = wm;
    }

    // (c) exact rescore: contiguous 256-B row per candidate; qkTf row uniform
    const int  m_l = (int)(__float_as_uint(mykey) & 0x7FFFu);
    const bool act = (lane < POOL);

    const float4* rm = (const float4*)(mkTf + (size_t)m_l * CKDIM);
    const float4* rq = (const float4*)(qkTf + (size_t)q * CKDIM);
    float dot = 0.f;
    #pragma unroll
    for (int g = 0; g < 16; ++g) {
        float4 a = rm[g];
        float4 b = rq[g];
        dot += a.x * b.x + a.y * b.y + a.z * b.z + a.w * b.w;
    }
    float aff = act ? (2.f * dot - asq[m_l]) * 0.125f : -INFINITY;

    __shared__ float kv[TOPK];
    __shared__ int   ki[TOPK];

    for (int r = 0; r < TOPK; ++r) {
        float bv = aff;
        int   bm = m_l;
        #pragma unroll
        for (int off = 32; off; off >>= 1) {
            float ov = __shfl_xor(bv, off);
            int   om = __shfl_xor(bm, off);
            if (ov > bv || (ov == bv && om < bm)) { bv = ov; bm = om; }
        }
        if (aff == bv && m_l == bm) aff = -INFINITY;   // deactivate winner (m unique)
        if (lane == 0) { kv[r] = bv; ki[r] = bm; }
    }
    __syncthreads();

    float e = (lane < TOPK) ? __expf(kv[lane] - kv[0]) : 0.f;
    float sum = e;
    #pragma unroll
    for (int off = 32; off; off >>= 1) sum += __shfl_xor(sum, off);

    if (lane < TOPK) {
        unsigned int wbits;
        { union { float f; unsigned int i; } u; u.f = e / sum; wbits = u.i; }
        qw[(size_t)q * TOPK + lane] = make_uint2((unsigned int)ki[lane], wbits);
    }
}

// ---------------------------------------------------------------------------
// K3: readout. Block (512 thr) per oc row; V row bf16 in LDS. Staging in two
// batches to bound VGPRs; q=tid's weights prefetched into registers before
// the barrier (qw L2 latency hidden under mv HBM staging).
// ---------------------------------------------------------------------------
__global__ __launch_bounds__(512, 4) void k_readout(const float* __restrict__ mv,
                                                    const uint2* __restrict__ qw,
                                                    float* __restrict__ out) {
    __shared__ unsigned short row[M_TOT];   // 64,800 B
    const int oc  = blockIdx.x;
    const int tid = threadIdx.x;

    const uint4* s4 = (const uint4*)(mv + (size_t)oc * M_TOT);
    ushort4* d4 = (ushort4*)row;

    // batch A: 8 chunks
    uint4 tA[8];
    #pragma unroll
    for (int it = 0; it < 8; ++it) tA[it] = s4[tid + it * 512];

    // prefetch q=tid weights (overlaps with staging loads)
    uint2 e0[TOPK];
    {
        const uint2* p0 = qw + (size_t)tid * TOPK;
        #pragma unroll
        for (int k = 0; k < TOPK; ++k) e0[k] = p0[k];
    }

    #pragma unroll
    for (int it = 0; it < 8; ++it) {
        uint4 v = tA[it];
        ushort4 h;
        h.x = f2bf(__uint_as_float(v.x));
        h.y = f2bf(__uint_as_float(v.y));
        h.z = f2bf(__uint_as_float(v.z));
        h.w = f2bf(__uint_as_float(v.w));
        d4[tid + it * 512] = h;
    }

    // batch B: 7 chunks + tail (total 8100 uint4)
    uint4 tB[7];
    #pragma unroll
    for (int it = 0; it < 7; ++it) tB[it] = s4[tid + (8 + it) * 512];
    uint4 tail;
    const int ti_idx = 15 * 512 + tid;   // 7680 + tid
    if (tid < M_TOT / 4 - 15 * 512)      // tid < 420
        tail = s4[ti_idx];

    #pragma unroll
    for (int it = 0; it < 7; ++it) {
        uint4 v = tB[it];
        ushort4 h;
        h.x = f2bf(__uint_as_float(v.x));
        h.y = f2bf(__uint_as_float(v.y));
        h.z = f2bf(__uint_as_float(v.z));
        h.w = f2bf(__uint_as_float(v.w));
        d4[tid + (8 + it) * 512] = h;
    }
    if (tid < M_TOT / 4 - 15 * 512) {
        ushort4 h;
        h.x = f2bf(__uint_as_float(tail.x));
        h.y = f2bf(__uint_as_float(tail.y));
        h.z = f2bf(__uint_as_float(tail.z));
        h.w = f2bf(__uint_as_float(tail.w));
        d4[ti_idx] = h;
    }
    __syncthreads();

    // q = tid (prefetched weights)
    {
        float acc = 0.f;
        #pragma unroll
        for (int k = 0; k < TOPK; ++k)
            acc += __uint_as_float(e0[k].y) * bf2f(row[e0[k].x]);
        out[(size_t)oc * QTOT + tid] = acc;
    }
    // q = tid + 512, +1024, +1536
    #pragma unroll
    for (int j = 1; j < 4; ++j) {
        int q = tid + j * 512;
        if (q >= QTOT) break;
        const uint2* p = qw + (size_t)q * TOPK;
        float acc = 0.f;
        #pragma unroll
        for (int k = 0; k < TOPK; ++k) {
            uint2 e = p[k];
            acc += __uint_as_float(e.y) * bf2f(row[e.x]);
        }
        out[(size_t)oc * QTOT + q] = acc;
    }
}

// ---------------------------------------------------------------------------
extern "C" void kernel_launch(void* const* d_in, const int* in_sizes, int n_in,
                              void* d_out, int out_size, void* d_ws, size_t ws_size,
                              hipStream_t stream) {
    const float* qk = (const float*)d_in[0];   // [64][1620] fp32
    const float* mk = (const float*)d_in[1];   // [64][32400] fp32
    const float* mv = (const float*)d_in[2];   // [1536][32400] fp32
    float* out = (float*)d_out;                // [1536][1620] fp32

    char* ws = (char*)d_ws;
    float*          asq   = (float*)(ws);                      // 129,600 B
    unsigned short* qkT   = (unsigned short*)(ws + 131072);    // 229,376 B
    unsigned short* mkT   = (unsigned short*)(ws + 360448);    // 4,147,200 B
    float*          mkTf  = (float*)(ws + 4507648);            // 8,294,400 B
    float*          qkTf  = (float*)(ws + 12802048);           // 458,752 B
    float*          pkeys = (float*)(ws + 13260800);           // 6,451,200 B
    uint2*          qw    = (uint2*)(ws + 19712000);           // 259,200 B
    // total ~= 20 MB

    k_prep     <<<dim3((M_TOT + QPAD + 255) / 256), dim3(256), 0, stream>>>(
                   mk, qk, asq, mkT, mkTf, qkT, qkTf);
    k_topk_mfma<<<dim3(28, NSPLIT),                 dim3(64),  0, stream>>>(mkT, qkT, asq, pkeys);
    k_select   <<<dim3(QTOT),                       dim3(64),  0, stream>>>(pkeys, mkTf, qkTf, asq, qw);
    k_readout  <<<dim3(OCDIM),                      dim3(512), 0, stream>>>(mv, qw, out);
}

// Round 7
// 354.010 us; speedup vs baseline: 3.7313x; 1.0449x over previous
//
#include <hip/hip_runtime.h>
#include <math.h>

// Problem constants (fixed by the reference; inputs are fp32)
#define M_TOT   32400
#define CKDIM   64
#define QTOT    1620
#define QPAD    1792      // 28 q-groups x 64
#define OCDIM   1536      // O*CV = 3*512
#define TOPK    20
#define NSPLIT  81        // 32400/81 = 400 m per split
#define MSPLIT  400
#define NTILES  25        // 25 m-tiles of 16 per split
#define KQUAD   3         // keys kept per (q, split, quad)
#define KSPLIT  (4*KQUAD) // 12 keys per (q, split)
#define KEYSQ   (NSPLIT*KSPLIT)   // 972 keys per query
#define POOL    32        // approx-global pool rescored exactly

typedef __attribute__((ext_vector_type(8))) short bf16x8;  // 8 bf16 (4 VGPRs)
typedef __attribute__((ext_vector_type(4))) float f32x4;

__device__ __forceinline__ float bf2f(unsigned short u) {
    union { unsigned int i; float f; } v;
    v.i = ((unsigned int)u) << 16;
    return v.f;
}

__device__ __forceinline__ unsigned short f2bf(float f) {
    union { float f; unsigned int i; } u;
    u.f = f;
    unsigned int r = u.i + 0x7FFF + ((u.i >> 16) & 1);  // RTNE
    return (unsigned short)(r >> 16);
}

__device__ __forceinline__ float med3f(float a, float b, float c) {
#if __has_builtin(__builtin_amdgcn_fmed3f)
    return __builtin_amdgcn_fmed3f(a, b, c);
#else
    return fmaxf(fminf(a, b), fminf(fmaxf(a, b), c));
#endif
}

// Branch-free insert of x into descending-sorted 3-list (med3 chain).
#define INS3(t, x) do {                    \
    t[2] = med3f((x), t[1], t[2]);         \
    t[1] = med3f((x), t[0], t[1]);         \
    t[0] = fmaxf(t[0], (x));               \
} while (0)

#define INS8(t, x) do {                    \
    t[7] = med3f((x), t[6], t[7]);         \
    t[6] = med3f((x), t[5], t[6]);         \
    t[5] = med3f((x), t[4], t[5]);         \
    t[4] = med3f((x), t[3], t[4]);         \
    t[3] = med3f((x), t[2], t[3]);         \
    t[2] = med3f((x), t[1], t[2]);         \
    t[1] = med3f((x), t[0], t[1]);         \
    t[0] = fmaxf(t[0], (x));               \
} while (0)

// ---------------------------------------------------------------------------
// K_prep: single pass producing asq, bf16 mkT/qkT (MFMA layout), fp32
// mkTf/qkTf (contiguous rescore rows).
// ---------------------------------------------------------------------------
__global__ __launch_bounds__(256) void k_prep(const float* __restrict__ mk,
                                              const float* __restrict__ qk,
                                              float* __restrict__ asq,
                                              unsigned short* __restrict__ mkT,
                                              float* __restrict__ mkTf,
                                              unsigned short* __restrict__ qkT,
                                              float* __restrict__ qkTf) {
    int idx = blockIdx.x * 256 + threadIdx.x;
    if (idx < M_TOT) {
        const int m = idx;
        float vals[CKDIM];
        float s = 0.f;
        #pragma unroll
        for (int c = 0; c < CKDIM; ++c) {
            vals[c] = mk[(size_t)c * M_TOT + m];
            s += vals[c] * vals[c];
        }
        asq[m] = s;
        uint4* db = (uint4*)(mkT + (size_t)m * CKDIM);
        #pragma unroll
        for (int g = 0; g < 8; ++g) {
            unsigned int r[4];
            #pragma unroll
            for (int p = 0; p < 4; ++p)
                r[p] = (unsigned int)f2bf(vals[g * 8 + 2 * p])
                     | ((unsigned int)f2bf(vals[g * 8 + 2 * p + 1]) << 16);
            db[g] = make_uint4(r[0], r[1], r[2], r[3]);
        }
        float4* df = (float4*)(mkTf + (size_t)m * CKDIM);
        #pragma unroll
        for (int g = 0; g < 16; ++g)
            df[g] = make_float4(vals[4 * g], vals[4 * g + 1], vals[4 * g + 2], vals[4 * g + 3]);
    } else if (idx < M_TOT + QPAD) {
        const int q = idx - M_TOT;
        float vals[CKDIM];
        #pragma unroll
        for (int c = 0; c < CKDIM; ++c)
            vals[c] = (q < QTOT) ? qk[(size_t)c * QTOT + q] : 0.f;
        uint4* db = (uint4*)(qkT + (size_t)q * CKDIM);
        #pragma unroll
        for (int g = 0; g < 8; ++g) {
            unsigned int r[4];
            #pragma unroll
            for (int p = 0; p < 4; ++p)
                r[p] = (unsigned int)f2bf(vals[g * 8 + 2 * p])
                     | ((unsigned int)f2bf(vals[g * 8 + 2 * p + 1]) << 16);
            db[g] = make_uint4(r[0], r[1], r[2], r[3]);
        }
        float4* df = (float4*)(qkTf + (size_t)q * CKDIM);
        #pragma unroll
        for (int g = 0; g < 16; ++g)
            df[g] = make_float4(vals[4 * g], vals[4 * g + 1], vals[4 * g + 2], vals[4 * g + 3]);
    }
}

// ---------------------------------------------------------------------------
// K1: MFMA affinity scan, register-resident selection on packed keys.
// grid = (28 q-groups, 81 splits), block = 1 wave; 2268 waves = 2.2/SIMD.
// Score = dot - 0.5*asq (monotone in affinity); key = (score & ~0x7FFF) | m.
// C/D layout (verified r3-r6): col=lane&15 (q), row=quad*4+reg (m).
// Per lane: top-3 per (its q-column qt, its m-quad) via med3 chain.
// ---------------------------------------------------------------------------
__global__ __launch_bounds__(64) void k_topk_mfma(const unsigned short* __restrict__ mkT,
                                                  const unsigned short* __restrict__ qkT,
                                                  const float* __restrict__ asq,
                                                  float* __restrict__ pkeys) {
    const int lane = threadIdx.x;
    const int l15  = lane & 15;
    const int quad = lane >> 4;
    const int q_base = blockIdx.x * 64;
    const int sp     = blockIdx.y;
    const int m_base = sp * MSPLIT;

    bf16x8 bF[4][2];
    #pragma unroll
    for (int qt = 0; qt < 4; ++qt) {
        const unsigned short* p = qkT + (size_t)(q_base + qt * 16 + l15) * CKDIM + quad * 8;
        bF[qt][0] = *(const bf16x8*)(p);
        bF[qt][1] = *(const bf16x8*)(p + 32);
    }

    float key3[4][KQUAD];
    #pragma unroll
    for (int qt = 0; qt < 4; ++qt)
        #pragma unroll
        for (int j = 0; j < KQUAD; ++j) key3[qt][j] = -INFINITY;

    // A-side base pointer for this lane (tile stride = 16 rows * 64 = 1024 shorts)
    const unsigned short* pa = mkT + (size_t)(m_base + l15) * CKDIM + quad * 8;

    // software-pipelined 25-tile loop (double-buffered A frags + asq)
    bf16x8 aF0 = *(const bf16x8*)(pa);
    bf16x8 aF1 = *(const bf16x8*)(pa + 32);
    f32x4  aq  = *(const f32x4*)(asq + m_base + quad * 4);

    for (int t = 0; t < NTILES; ++t) {
        bf16x8 nF0, nF1;
        f32x4  naq;
        if (t + 1 < NTILES) {
            const unsigned short* pn = pa + (size_t)(t + 1) * 1024;
            nF0 = *(const bf16x8*)(pn);
            nF1 = *(const bf16x8*)(pn + 32);
            naq = *(const f32x4*)(asq + m_base + (t + 1) * 16 + quad * 4);
        }
        f32x4 cinit = -0.5f * aq;
        const unsigned int mq = (unsigned int)(m_base + t * 16 + quad * 4);
        #pragma unroll
        for (int qt = 0; qt < 4; ++qt) {
            f32x4 c = cinit;
            c = __builtin_amdgcn_mfma_f32_16x16x32_bf16(aF0, bF[qt][0], c, 0, 0, 0);
            c = __builtin_amdgcn_mfma_f32_16x16x32_bf16(aF1, bF[qt][1], c, 0, 0, 0);
            #pragma unroll
            for (int i = 0; i < 4; ++i) {
                unsigned int kb = (__float_as_uint(c[i]) & 0xFFFF8000u) | (mq + i);
                float kf = __uint_as_float(kb);
                INS3(key3[qt], kf);
            }
        }
        aF0 = nF0; aF1 = nF1; aq = naq;
    }

    #pragma unroll
    for (int qt = 0; qt < 4; ++qt) {
        const int q = q_base + qt * 16 + l15;
        float* dst = pkeys + (size_t)q * KEYSQ + sp * KSPLIT + quad * KQUAD;
        #pragma unroll
        for (int j = 0; j < KQUAD; ++j) dst[j] = key3[qt][j];
    }
}

// ---------------------------------------------------------------------------
// K2: fused select. One wave per query:
//  (a) lane-local sorted top-8 over strided 972 keys,
//  (b) 32-round tournament pop -> register-resident pool,
//  (c) exact fp32 rescore (contiguous mkTf rows), top-20 + softmax.
// ---------------------------------------------------------------------------
__global__ __launch_bounds__(64) void k_select(const float* __restrict__ pkeys,
                                               const float* __restrict__ mkTf,
                                               const float* __restrict__ qkTf,
                                               const float* __restrict__ asq,
                                               uint2* __restrict__ qw) {
    const int q    = blockIdx.x;
    const int lane = threadIdx.x;

    // (a) local top-8 over 972 keys (16 strided passes, last partial)
    float t[8];
    #pragma unroll
    for (int j = 0; j < 8; ++j) t[j] = -INFINITY;
    const float* src = pkeys + (size_t)q * KEYSQ;
    #pragma unroll
    for (int i = 0; i < 16; ++i) {
        int s = lane + i * 64;
        float v = (s < KEYSQ) ? src[s] : -INFINITY;
        INS8(t, v);
    }

    // (b) tournament: pop global max 32 times
    float mykey = -INFINITY;
    for (int r = 0; r < POOL; ++r) {
        float h = t[0];
        float wm = h;
        #pragma unroll
        for (int off = 32; off; off >>= 1) wm = fmaxf(wm, __shfl_xor(wm, off));
        bool win = (h == wm);
        t[0] = win ? t[1] : t[0];
        t[1] = win ? t[2] : t[1];
        t[2] = win ? t[3] : t[2];
        t[3] = win ? t[4] : t[3];
        t[4] = win ? t[5] : t[4];
        t[5] = win ? t[6] : t[5];
        t[6] = win ? t[7] : t[6];
        t[7] = win ? -INFINITY : t[7];
        if (lane == r) mykey = wm;
    }

    // (c) exact rescore: contiguous 256-B row per candidate; qkTf row uniform
    const int  m_l = (int)(__float_as_uint(mykey) & 0x7FFFu);
    const bool act = (lane < POOL);

    const float4* rm = (const float4*)(mkTf + (size_t)m_l * CKDIM);
    const float4* rq = (const float4*)(qkTf + (size_t)q * CKDIM);
    float dot = 0.f;
    #pragma unroll
    for (int g = 0; g < 16; ++g) {
        float4 a = rm[g];
        float4 b = rq[g];
        dot += a.x * b.x + a.y * b.y + a.z * b.z + a.w * b.w;
    }
    float aff = act ? (2.f * dot - asq[m_l]) * 0.125f : -INFINITY;

    __shared__ float kv[TOPK];
    __shared__ int   ki[TOPK];

    for (int r = 0; r < TOPK; ++r) {
        float bv = aff;
        int   bm = m_l;
        #pragma unroll
        for (int off = 32; off; off >>= 1) {
            float ov = __shfl_xor(bv, off);
            int   om = __shfl_xor(bm, off);
            if (ov > bv || (ov == bv && om < bm)) { bv = ov; bm = om; }
        }
        if (aff == bv && m_l == bm) aff = -INFINITY;   // deactivate winner (m unique)
        if (lane == 0) { kv[r] = bv; ki[r] = bm; }
    }
    __syncthreads();

    float e = (lane < TOPK) ? __expf(kv[lane] - kv[0]) : 0.f;
    float sum = e;
    #pragma unroll
    for (int off = 32; off; off >>= 1) sum += __shfl_xor(sum, off);

    if (lane < TOPK) {
        unsigned int wbits;
        { union { float f; unsigned int i; } u; u.f = e / sum; wbits = u.i; }
        qw[(size_t)q * TOPK + lane] = make_uint2((unsigned int)ki[lane], wbits);
    }
}

// ---------------------------------------------------------------------------
// K3: readout (proven r4-r6). Block (512 thr) per oc row; V row bf16 in LDS;
// two staging batches; q=tid weights prefetched under staging latency.
// ---------------------------------------------------------------------------
__global__ __launch_bounds__(512, 4) void k_readout(const float* __restrict__ mv,
                                                    const uint2* __restrict__ qw,
                                                    float* __restrict__ out) {
    __shared__ unsigned short row[M_TOT];   // 64,800 B
    const int oc  = blockIdx.x;
    const int tid = threadIdx.x;

    const uint4* s4 = (const uint4*)(mv + (size_t)oc * M_TOT);
    ushort4* d4 = (ushort4*)row;

    uint4 tA[8];
    #pragma unroll
    for (int it = 0; it < 8; ++it) tA[it] = s4[tid + it * 512];

    uint2 e0[TOPK];
    {
        const uint2* p0 = qw + (size_t)tid * TOPK;
        #pragma unroll
        for (int k = 0; k < TOPK; ++k) e0[k] = p0[k];
    }

    #pragma unroll
    for (int it = 0; it < 8; ++it) {
        uint4 v = tA[it];
        ushort4 h;
        h.x = f2bf(__uint_as_float(v.x));
        h.y = f2bf(__uint_as_float(v.y));
        h.z = f2bf(__uint_as_float(v.z));
        h.w = f2bf(__uint_as_float(v.w));
        d4[tid + it * 512] = h;
    }

    uint4 tB[7];
    #pragma unroll
    for (int it = 0; it < 7; ++it) tB[it] = s4[tid + (8 + it) * 512];
    uint4 tail;
    const int ti_idx = 15 * 512 + tid;   // 7680 + tid
    if (tid < M_TOT / 4 - 15 * 512)      // tid < 420
        tail = s4[ti_idx];

    #pragma unroll
    for (int it = 0; it < 7; ++it) {
        uint4 v = tB[it];
        ushort4 h;
        h.x = f2bf(__uint_as_float(v.x));
        h.y = f2bf(__uint_as_float(v.y));
        h.z = f2bf(__uint_as_float(v.z));
        h.w = f2bf(__uint_as_float(v.w));
        d4[tid + (8 + it) * 512] = h;
    }
    if (tid < M_TOT / 4 - 15 * 512) {
        ushort4 h;
        h.x = f2bf(__uint_as_float(tail.x));
        h.y = f2bf(__uint_as_float(tail.y));
        h.z = f2bf(__uint_as_float(tail.z));
        h.w = f2bf(__uint_as_float(tail.w));
        d4[ti_idx] = h;
    }
    __syncthreads();

    {
        float acc = 0.f;
        #pragma unroll
        for (int k = 0; k < TOPK; ++k)
            acc += __uint_as_float(e0[k].y) * bf2f(row[e0[k].x]);
        out[(size_t)oc * QTOT + tid] = acc;
    }
    #pragma unroll
    for (int j = 1; j < 4; ++j) {
        int q = tid + j * 512;
        if (q >= QTOT) break;
        const uint2* p = qw + (size_t)q * TOPK;
        float acc = 0.f;
        #pragma unroll
        for (int k = 0; k < TOPK; ++k) {
            uint2 e = p[k];
            acc += __uint_as_float(e.y) * bf2f(row[e.x]);
        }
        out[(size_t)oc * QTOT + q] = acc;
    }
}

// ---------------------------------------------------------------------------
extern "C" void kernel_launch(void* const* d_in, const int* in_sizes, int n_in,
                              void* d_out, int out_size, void* d_ws, size_t ws_size,
                              hipStream_t stream) {
    const float* qk = (const float*)d_in[0];   // [64][1620] fp32
    const float* mk = (const float*)d_in[1];   // [64][32400] fp32
    const float* mv = (const float*)d_in[2];   // [1536][32400] fp32
    float* out = (float*)d_out;                // [1536][1620] fp32

    char* ws = (char*)d_ws;
    float*          asq   = (float*)(ws);                      // 129,600 B
    unsigned short* qkT   = (unsigned short*)(ws + 131072);    // 229,376 B
    unsigned short* mkT   = (unsigned short*)(ws + 360448);    // 4,147,200 B
    float*          mkTf  = (float*)(ws + 4507648);            // 8,294,400 B
    float*          qkTf  = (float*)(ws + 12802048);           // 458,752 B
    float*          pkeys = (float*)(ws + 13260800);           // 1792*972*4 = 6,967,296 B
    uint2*          qw    = (uint2*)(ws + 20228096);           // 259,200 B
    // total ~= 20.5 MB

    k_prep     <<<dim3((M_TOT + QPAD + 255) / 256), dim3(256), 0, stream>>>(
                   mk, qk, asq, mkT, mkTf, qkT, qkTf);
    k_topk_mfma<<<dim3(28, NSPLIT),                 dim3(64),  0, stream>>>(mkT, qkT, asq, pkeys);
    k_select   <<<dim3(QTOT),                       dim3(64),  0, stream>>>(pkeys, mkTf, qkTf, asq, qw);
    k_readout  <<<dim3(OCDIM),                      dim3(512), 0, stream>>>(mv, qw, out);
}